// Round 3
// baseline (344.334 us; speedup 1.0000x reference)
//
#include <hip/hip_runtime.h>

// Problem constants (from setup_inputs): B=4, H=384, W=512, C=64, fp32.
constexpr int B = 4, H = 384, W = 512, C = 64;
constexpr int HW = H * W;              // 196608
constexpr int C4 = C / 4;              // 16 float4 chunks per pixel

// Native clang vector type — required by __builtin_nontemporal_store
// (HIP_vector_type<float,4> is rejected). Same 16-byte layout as float4.
typedef float f32x4 __attribute__((ext_vector_type(4)));
typedef float f32x2 __attribute__((ext_vector_type(2)));

// 16 consecutive threads handle one output pixel (one float4 of channels each):
// each bilinear tap is a contiguous 256 B row in feature -> fully coalesced.
// blockIdx.y = batch index (avoids integer div by HW in the hot path).
__global__ __launch_bounds__(256) void warp_kernel(
    const f32x2* __restrict__ flow,    // (B,H,W,2) viewed as float2
    const f32x4* __restrict__ feat,    // (B,H,W,C) viewed as float4
    const float* __restrict__ mask,    // (H,W)
    f32x4* __restrict__ out)           // (B,H,W,C) viewed as float4
{
    int gid = blockIdx.x * 256 + threadIdx.x;   // over HW * C4
    int b   = blockIdx.y;
    int c4  = gid & (C4 - 1);   // which float4 chunk of the channel dim
    int hw  = gid >> 4;         // pixel within the image
    int xg  = hw & (W - 1);     // W = 512 (pow2)
    int yg  = hw >> 9;
    int pix = b * HW + hw;

    // flow (same value across the 16-lane group -> broadcast from cache)
    f32x2 f = flow[pix];
    float xt = (float)xg + f.x;
    float yt = (float)yg + f.y;

    // faithful to reference: x = (2*xt/(W-1) - 1 + 1) * 0.5 * W  (= xt * W/(W-1))
    float x = (2.0f * xt / (float)(W - 1)) * 0.5f * (float)W;
    float y = (2.0f * yt / (float)(H - 1)) * 0.5f * (float)H;

    // reference clamps the INT coords, then derives weights from the clamped values
    int x0 = min(max((int)floorf(x), 0), W - 1);
    int x1 = min(x0 + 1, W - 1);
    int y0 = min(max((int)floorf(y), 0), H - 1);
    int y1 = min(y0 + 1, H - 1);
    float x0f = (float)x0, x1f = (float)x1;
    float y0f = (float)y0, y1f = (float)y1;

    float wa = (x1f - x) * (y1f - y);
    float wb = (x1f - x) * (y - y0f);
    float wc = (x - x0f) * (y1f - y);
    float wd = (x - x0f) * (y - y0f);

    float m = mask[hw];

    int base = b * HW;
    f32x4 va = feat[(base + y0 * W + x0) * C4 + c4];
    f32x4 vb = feat[(base + y1 * W + x0) * C4 + c4];
    f32x4 vc = feat[(base + y0 * W + x1) * C4 + c4];
    f32x4 vd = feat[(base + y1 * W + x1) * C4 + c4];

    f32x4 r = (wa * va + wb * vb + wc * vc + wd * vd) * m;

    // Non-temporal: output is write-once; keep it from evicting feature in L2/L3.
    __builtin_nontemporal_store(r, &out[pix * C4 + c4]);
}

extern "C" void kernel_launch(void* const* d_in, const int* in_sizes, int n_in,
                              void* d_out, int out_size, void* d_ws, size_t ws_size,
                              hipStream_t stream) {
    const f32x2* flow = (const f32x2*)d_in[0];   // w: (B,H,W,2)
    const f32x4* feat = (const f32x4*)d_in[1];   // feature: (B,H,W,C)
    const float* mask = (const float*)d_in[2];   // mask: (H,W)
    f32x4* out = (f32x4*)d_out;

    dim3 grid(HW * C4 / 256, B), block(256);
    warp_kernel<<<grid, block, 0, stream>>>(flow, feat, mask, out);
}